// Round 7
// baseline (2238.788 us; speedup 1.0000x reference)
//
#include <hip/hip_runtime.h>
#include <math.h>
#include <stdint.h>

#define NTAGS 512
#define SEQL  512
#define BATCH 64
#define START_TAG 510
#define STOP_TAG  511
#define NEG_INF  -10000.0f

// Intra-XCD machine: the 512-step chain is latency-bound on publish->poll through the
// die-level coherence point (~1.4us/step, R0/R5). Blocks on ONE XCD share a coherent L2
// (L1 is write-through; volatile loads bypass L1), so a 32-block single-XCD machine can
// exchange at ~L2 latency. 448 blocks claim via HW_REG_XCC_ID tickets; first XCD to fill
// NPART tickets wins (pigeonhole over 448 claimers guarantees a winner even if the hwreg
// read is garbage); losers exit. 64 more blocks (bid>=448) compute the numerator.
// EVERY risky mechanism has a proven fallback: publishers dual-store (volatile + agent),
// pollers switch to R0's agent-scope poll after SPIN_BUDGET misses -> worst case ~R0 perf.
#define NGRID  512
#define BT     512
#define NCLAIM 448
#define NPART  32               // participant blocks (CUs on the winner XCD)
#define RPB    16               // rows per participant block
#define RPW    2                // rows per wave
#define REPS   8                // slot replicas; block polls replica tkt&7
#define SPIN_BUDGET 256         // volatile-poll rounds before permanent agent fallback

// ws layout (bytes) — total 33 KB, well under the R0-proven 65792-byte footprint.
#define WS_NUM_OFF  0           // float numerator accumulator
#define WS_DONE_OFF 8           // int: numerator blocks retired
#define WS_WIN_OFF  16          // int: winner xcd+1 (0 = undecided)
#define WS_CNT_OFF  64          // int xcdcnt[8]
#define WS_SLOT_OFF 256         // u32 slots[2][REPS][NTAGS]; value in bits 0-30 (w in [1,512],
                                // sign always 0), level-tag in bit 31. tag(L)=((L+1)>>1)&1
                                // alternates per reuse of each depth-2 half and is 1 on first
                                // use, so memset-zero can never false-fire. 4B = tear-free.
#define WS_BYTES    (WS_SLOT_OFF + 2 * REPS * NTAGS * 4)

#define AGLD(p)      __hip_atomic_load((p),      __ATOMIC_RELAXED, __HIP_MEMORY_SCOPE_AGENT)
#define AGSTORE(p,v) __hip_atomic_store((p),(v), __ATOMIC_RELAXED, __HIP_MEMORY_SCOPE_AGENT)

__global__ __launch_bounds__(BT) void crf_fused(
    const float* __restrict__ inputs, const int* __restrict__ tags,
    const float* __restrict__ trans, void* __restrict__ ws,
    float* __restrict__ out)
{
    __shared__ float wlds[2][NTAGS];        // 4 KB ping-pong of w = exp(fv)
    __shared__ int   sh_tkt, sh_win;

    const int tid  = threadIdx.x;
    const int bid  = blockIdx.x;
    const int lane = tid & 63;
    const int wave = tid >> 6;

    float*    numacc  = (float*)((char*)ws + WS_NUM_OFF);
    int*      numdone = (int*)  ((char*)ws + WS_DONE_OFF);
    int*      winner  = (int*)  ((char*)ws + WS_WIN_OFF);
    int*      xcdcnt  = (int*)  ((char*)ws + WS_CNT_OFF);
    uint32_t* slots   = (uint32_t*)((char*)ws + WS_SLOT_OFF);

    // ================= numerator blocks (R0-verbatim math; proven agent atomics) =========
    if (bid >= NCLAIM) {
        const int b = bid - NCLAIM;
        const int*   tg  = tags + b * SEQL;
        const float* inb = inputs + (size_t)b * SEQL * NTAGS;
        float ns;
        if (tid > 0) {
            const int cur = tg[tid], prev = tg[tid - 1];
            ns = trans[cur * NTAGS + prev] + inb[(size_t)(tid - 1) * NTAGS + cur];
        } else {
            ns = trans[tg[0] * NTAGS + START_TAG] + trans[STOP_TAG * NTAGS + tg[SEQL - 1]];
        }
        #pragma unroll
        for (int off = 32; off; off >>= 1) ns += __shfl_xor(ns, off);
        if (lane == 0) atomicAdd(numacc, ns);
        __builtin_amdgcn_s_waitcnt(0);      // RMW retired at coherence point
        __syncthreads();
        if (tid == 0) atomicAdd(numdone, 1);
        return;
    }

    // ================= XCD claim: first XCD to fill NPART tickets wins ====================
    const int xcd = __builtin_amdgcn_s_getreg((31 << 11) | 20) & 7;  // hwreg(HW_REG_XCC_ID,0,32)
    if (tid == 0) {
        const int t = atomicAdd(&xcdcnt[xcd], 1);
        sh_tkt = t;
        if (t == NPART - 1) atomicCAS(winner, 0, xcd + 1);
        int w;
        do { w = AGLD(winner); } while (w == 0);    // fires by pigeonhole (448/8 -> max>=56)
        sh_win = w - 1;
    }
    __syncthreads();
    const int tkt = sh_tkt;
    if (xcd != sh_win || tkt >= NPART) return;      // loser XCD / surplus ticket

    // ================= participant: rows [16*tkt, 16*tkt+16); wave owns 2 rows ============
    const int r0 = RPB * tkt + RPW * wave;

    // transition rows in EXP space (absmax=0-validated R1-R5): treg[i][q]=exp(T[r0+i][lane+64q]).
    // START row is uniformly -1e4 -> shift to exp(0)=1 (p/q invariant to uniform row scale).
    float treg[RPW][8];
    #pragma unroll
    for (int i = 0; i < RPW; ++i) {
        const int   r     = r0 + i;
        const float shift = (r == START_TAG) ? -NEG_INF : 0.0f;
        const float* trow = trans + (size_t)r * NTAGS;
        #pragma unroll
        for (int q = 0; q < 8; ++q)
            treg[i][q] = __expf(trow[lane + 64 * q] + shift);
    }

    wlds[0][tid] = (tid == START_TAG) ? 1.0f : 0.0f;   // w_0 one-hot (level 0 never published)
    __syncthreads();

    volatile uint32_t* vslots = (volatile uint32_t*)slots;
    int use_mirror = 0;     // sticky per-thread: volatile fast path failed -> agent poll

    for (int s = 0; s < SEQL; ++s) {
        const int      L      = s + 1;
        const int      ph     = s & 1, nxt = ph ^ 1;           // level L lives in half L&1==nxt
        const uint32_t tagbit = (uint32_t)(((L + 1) >> 1) & 1) << 31;
        const uint32_t tag    = tagbit >> 31;
        const size_t   base   = (size_t)nxt * REPS * NTAGS;
        const size_t   myoff  = base + (size_t)(tkt & 7) * NTAGS + tid;

        // ---- 2 rows: t = w .* E[row]; sp = sum tree, mq = max tree (R5-identical order) ----
        float wv[8];
        #pragma unroll
        for (int q = 0; q < 8; ++q)
            wv[q] = wlds[ph][lane + 64 * q];                   // 2-way LDS alias only (free)

        float sp[RPW], mq[RPW];
        #pragma unroll
        for (int i = 0; i < RPW; ++i) {
            const float t0 = wv[0] * treg[i][0], t1 = wv[1] * treg[i][1],
                        t2 = wv[2] * treg[i][2], t3 = wv[3] * treg[i][3],
                        t4 = wv[4] * treg[i][4], t5 = wv[5] * treg[i][5],
                        t6 = wv[6] * treg[i][6], t7 = wv[7] * treg[i][7];
            sp[i] = ((t0 + t1) + (t2 + t3)) + ((t4 + t5) + (t6 + t7));
            mq[i] = fmaxf(fmaxf(fmaxf(t0, t1), fmaxf(t2, t3)),
                          fmaxf(fmaxf(t4, t5), fmaxf(t6, t7)));
        }
        #pragma unroll
        for (int off = 32; off; off >>= 1) {                   // 4 butterflies interleaved
            #pragma unroll
            for (int i = 0; i < RPW; ++i) {
                const float a = __shfl_xor(sp[i], off);
                const float b = __shfl_xor(mq[i], off);
                sp[i] += a; mq[i] = fmaxf(mq[i], b);
            }
        }

        // ---- publish: lanes 0-15 volatile (XCD L2), lanes 16-31 agent (coherence point) ----
        if (lane < 32) {
            const int   i  = (lane >> 3) & 1;                  // 0-7,16-23 -> row r0; 8-15,24-31 -> r0+1
            const int   rp = lane & 7;
            const float wn = __fdividef(sp[i], mq[i]);         // w in [1,512]: sign bit 0
            const uint32_t pk = __float_as_uint(wn) | tagbit;
            uint32_t* dst = slots + base + (size_t)rp * NTAGS + (r0 + i);
            if (lane < 16) *(volatile uint32_t*)dst = pk;
            else           AGSTORE(dst, pk);
        }

        // ---- poll MY slot: volatile fast path, 4 loads in flight; agent fallback ----
        uint32_t p = 0;
        int got = 0;
        if (!use_mirror) {
            p = vslots[myoff];
            if ((p >> 31) == tag) got = 1;
            else {
                int it = 0;
                uint32_t q0 = vslots[myoff], q1 = vslots[myoff],
                         q2 = vslots[myoff], q3 = vslots[myoff];
                for (;;) {
                    if ((q0 >> 31) == tag) { p = q0; got = 1; break; }
                    q0 = vslots[myoff];
                    if ((q1 >> 31) == tag) { p = q1; got = 1; break; }
                    q1 = vslots[myoff];
                    if ((q2 >> 31) == tag) { p = q2; got = 1; break; }
                    q2 = vslots[myoff];
                    if ((q3 >> 31) == tag) { p = q3; got = 1; break; }
                    q3 = vslots[myoff];
                    if (++it > SPIN_BUDGET) { use_mirror = 1; break; }   // deadman
                }
            }
        }
        if (!got) {                                            // R0-proven universal path
            p = AGLD(slots + myoff);
            while ((p >> 31) != tag) p = AGLD(slots + myoff);
        }

        wlds[nxt][tid] = __uint_as_float(p & 0x7FFFFFFFu);
        __syncthreads();                                       // one sync per step (R0)
    }

    // ================= terminal: tkt 31, wave 7 owns rows 510,511 (i=1 == STOP) ===========
    if (tkt == NPART - 1 && wave == 7) {
        float t[8];
        #pragma unroll
        for (int q = 0; q < 8; ++q)
            t[q] = wlds[0][lane + 64 * q] * treg[1][q];        // w_512 in buffer 0 (512 even)
        float sp = ((t[0] + t[1]) + (t[2] + t[3])) + ((t[4] + t[5]) + (t[6] + t[7]));
        float mq = fmaxf(fmaxf(fmaxf(t[0], t[1]), fmaxf(t[2], t[3])),
                         fmaxf(fmaxf(t[4], t[5]), fmaxf(t[6], t[7])));
        #pragma unroll
        for (int off = 32; off; off >>= 1) {
            const float a = __shfl_xor(sp, off);
            const float b = __shfl_xor(mq, off);
            sp += a; mq = fmaxf(mq, b);
        }
        if (lane == 0) {
            while (AGLD(numdone) < BATCH) {}                   // all numerator blocks retired
            const float ld  = __logf(sp) - __logf(mq);         // log_denominator (batch-invariant)
            const float num = AGLD(numacc);
            out[0] = num - (float)BATCH * ld;
        }
    }
}

extern "C" void kernel_launch(void* const* d_in, const int* in_sizes, int n_in,
                              void* d_out, int out_size, void* d_ws, size_t ws_size,
                              hipStream_t stream)
{
    const float* inputs = (const float*)d_in[0];   // (64, 512, 512) fp32
    const int*   tags   = (const int*)  d_in[1];   // (64, 512) int32
    const float* trans  = (const float*)d_in[2];   // (512, 512) fp32
    float* out = (float*)d_out;

    // zero header + 32KB slot array (33KB total, under the R0-proven ws footprint)
    hipMemsetAsync(d_ws, 0, WS_BYTES, stream);

    crf_fused<<<NGRID, BT, 0, stream>>>(inputs, tags, trans, d_ws, out);
}

// Round 8
// 908.836 us; speedup vs baseline: 2.4634x; 2.4634x over previous
//
#include <hip/hip_runtime.h>
#include <math.h>
#include <stdint.h>

#define NTAGS 512
#define SEQL  512
#define BATCH 64
#define START_TAG 510
#define STOP_TAG  511
#define NEG_INF  -10000.0f

// 32 chain blocks (x 8 waves x 2 rows/wave) + 32 numerator blocks (2 batches each).
// R7 lesson: intra-XCD rendezvous unreachable from HIP volatile (goes to LLC anyway) and
// one-XCD concentration serializes on a single fabric port. So: keep R0's LLC protocol
// bit-for-bit, halve the participant count + poll traffic, move the numerator off-path.
#define NB     64
#define BT     512
#define NCHAIN 32               // chain blocks: block b owns rows [16b, 16b+16)
#define RPW    2                // rows per wave: wave w owns rows 16b+2w, 16b+2w+1
#define REPS   8                // slot replicas; chain block polls replica bid&7

// ws layout (bytes) — 65792 total, the R0-proven footprint.
#define WS_NUM_OFF  0                     // float numerator accumulator
#define WS_DONE_OFF 8                     // int: numerator blocks retired
#define WS_SLOT_OFF 256                   // u64 slots [2][REPS][NTAGS]: (step<<32)|f32bits
#define WS_BYTES    (WS_SLOT_OFF + 2 * REPS * NTAGS * 8)

#define AGLD(p)   __hip_atomic_load((p),      __ATOMIC_RELAXED, __HIP_MEMORY_SCOPE_AGENT)
#define AGST(p,v) __hip_atomic_store((p),(v), __ATOMIC_RELAXED, __HIP_MEMORY_SCOPE_AGENT)

__global__ __launch_bounds__(BT) void crf_fused(
    const float* __restrict__ inputs, const int* __restrict__ tags,
    const float* __restrict__ trans, void* __restrict__ ws,
    float* __restrict__ out)
{
    __shared__ float wlds[2][NTAGS];        // 4 KB ping-pong of w = exp(fv)

    const int tid  = threadIdx.x;
    const int bid  = blockIdx.x;
    const int lane = tid & 63;
    const int wave = tid >> 6;

    float*    numacc  = (float*)((char*)ws + WS_NUM_OFF);
    int*      numdone = (int*)  ((char*)ws + WS_DONE_OFF);
    uint64_t* slots   = (uint64_t*)((char*)ws + WS_SLOT_OFF);

    // ================= numerator blocks: bid in [32,64), 2 batches each (off the chain) ====
    if (bid >= NCHAIN) {
        #pragma unroll
        for (int it = 0; it < 2; ++it) {
            const int    b   = (bid - NCHAIN) * 2 + it;
            const int*   tg  = tags + b * SEQL;
            const float* inb = inputs + (size_t)b * SEQL * NTAGS;
            float ns;
            if (tid > 0) {
                const int cur = tg[tid], prev = tg[tid - 1];
                ns = trans[cur * NTAGS + prev] + inb[(size_t)(tid - 1) * NTAGS + cur];
            } else {
                ns = trans[tg[0] * NTAGS + START_TAG] + trans[STOP_TAG * NTAGS + tg[SEQL - 1]];
            }
            #pragma unroll
            for (int off = 32; off; off >>= 1) ns += __shfl_xor(ns, off);
            if (lane == 0) atomicAdd(numacc, ns);
        }
        __builtin_amdgcn_s_waitcnt(0);      // numacc RMWs retired at coherence point
        __syncthreads();                    // all 8 waves done
        if (tid == 0) atomicAdd(numdone, 1);
        return;
    }

    // ================= chain block: rows [16*bid, 16*bid+16); wave owns 2 rows =============
    const int r0  = 16 * bid + RPW * wave;
    const int rep = bid & (REPS - 1);

    // transition rows in EXP space (absmax=0-validated R1-R5,R7): treg[i][q]=exp(T[r0+i][lane+64q]).
    // START row is uniformly -1e4 -> shift to exp(0)=1 (w'=p/q invariant to uniform row scale).
    float treg[RPW][8];
    #pragma unroll
    for (int i = 0; i < RPW; ++i) {
        const int   r     = r0 + i;
        const float shift = (r == START_TAG) ? -NEG_INF : 0.0f;
        const float* trow = trans + (size_t)r * NTAGS;
        #pragma unroll
        for (int q = 0; q < 8; ++q)
            treg[i][q] = __expf(trow[lane + 64 * q] + shift);   // coalesced 256B/wave
    }

    // w_0: one-hot at START (level 0 never published)
    wlds[0][tid] = (tid == START_TAG) ? 1.0f : 0.0f;
    __syncthreads();

    for (int s = 0; s < SEQL; ++s) {
        const int ph = s & 1, nxt = ph ^ 1;                      // wlds[ph] = w_s
        uint64_t* pubbase = slots + (size_t)nxt * REPS * NTAGS;
        uint64_t* myslot  = slots + ((size_t)nxt * REPS + rep) * NTAGS + tid;
        const unsigned want = (unsigned)(s + 1);

        // early probe: overlaps compute + publish (others' s+1 may already have arrived)
        uint64_t p = AGLD(myslot);

        // ---- 2 rows: t = w .* E[row]; sp = sum tree, mq = max tree (R2/R7-identical order) ----
        float wv[8];
        #pragma unroll
        for (int q = 0; q < 8; ++q)
            wv[q] = wlds[ph][lane + 64 * q];                     // 2-way LDS alias only (free)

        float sp[RPW], mq[RPW];
        #pragma unroll
        for (int i = 0; i < RPW; ++i) {
            const float t0 = wv[0] * treg[i][0], t1 = wv[1] * treg[i][1],
                        t2 = wv[2] * treg[i][2], t3 = wv[3] * treg[i][3],
                        t4 = wv[4] * treg[i][4], t5 = wv[5] * treg[i][5],
                        t6 = wv[6] * treg[i][6], t7 = wv[7] * treg[i][7];
            sp[i] = ((t0 + t1) + (t2 + t3)) + ((t4 + t5) + (t6 + t7));
            mq[i] = fmaxf(fmaxf(fmaxf(t0, t1), fmaxf(t2, t3)),
                          fmaxf(fmaxf(t4, t5), fmaxf(t6, t7)));
        }
        #pragma unroll
        for (int off = 32; off; off >>= 1) {                     // 4 butterflies interleaved
            #pragma unroll
            for (int i = 0; i < RPW; ++i) {
                const float a = __shfl_xor(sp[i], off);
                const float b = __shfl_xor(mq[i], off);
                sp[i] += a; mq[i] = fmaxf(mq[i], b);
            }
        }

        // ---- publish: lanes 0-15 cover 2 rows x 8 replicas in ONE instruction ----
        if (lane < 2 * REPS) {
            const int   i  = lane >> 3, rp = lane & 7;
            const float wn = __fdividef(sp[i], mq[i]);           // w in [1,512]: bits never 0
            const uint64_t pk = ((uint64_t)want << 32) | (uint64_t)__float_as_uint(wn);
            AGST(pubbase + (size_t)rp * NTAGS + (r0 + i), pk);
        }

        // ---- pipelined poll of MY single slot (replica bid&7): 4 loads in flight (R0) ----
        if ((unsigned)(p >> 32) != want) {
            uint64_t q0 = AGLD(myslot), q1 = AGLD(myslot),
                     q2 = AGLD(myslot), q3 = AGLD(myslot);
            for (;;) {
                if ((unsigned)(q0 >> 32) == want) { p = q0; break; }
                q0 = AGLD(myslot);
                if ((unsigned)(q1 >> 32) == want) { p = q1; break; }
                q1 = AGLD(myslot);
                if ((unsigned)(q2 >> 32) == want) { p = q2; break; }
                q2 = AGLD(myslot);
                if ((unsigned)(q3 >> 32) == want) { p = q3; break; }
                q3 = AGLD(myslot);
            }
        }
        wlds[nxt][tid] = __uint_as_float((unsigned)(p & 0xFFFFFFFFu));
        __syncthreads();   // depth-2 ping-pong: one sync per step suffices (R0)
    }

    // ================= terminal: block 31, wave 7 owns rows 510,511 (i=1 == STOP) ==========
    if (bid == NCHAIN - 1 && wave == 7) {
        float t[8];
        #pragma unroll
        for (int q = 0; q < 8; ++q)
            t[q] = wlds[0][lane + 64 * q] * treg[1][q];          // w_512 in buffer 0 (512 even)
        float sp = ((t[0] + t[1]) + (t[2] + t[3])) + ((t[4] + t[5]) + (t[6] + t[7]));
        float mq = fmaxf(fmaxf(fmaxf(t[0], t[1]), fmaxf(t[2], t[3])),
                         fmaxf(fmaxf(t[4], t[5]), fmaxf(t[6], t[7])));
        #pragma unroll
        for (int off = 32; off; off >>= 1) {
            const float a = __shfl_xor(sp, off);
            const float b = __shfl_xor(mq, off);
            sp += a; mq = fmaxf(mq, b);
        }
        if (lane == 0) {
            while (AGLD(numdone) < NB - NCHAIN) {}               // all numerator blocks retired
            const float ld  = __logf(sp) - __logf(mq);           // log_denominator (batch-invariant)
            const float num = AGLD(numacc);
            out[0] = num - (float)BATCH * ld;
        }
    }
}

extern "C" void kernel_launch(void* const* d_in, const int* in_sizes, int n_in,
                              void* d_out, int out_size, void* d_ws, size_t ws_size,
                              hipStream_t stream)
{
    const float* inputs = (const float*)d_in[0];   // (64, 512, 512) fp32
    const int*   tags   = (const int*)  d_in[1];   // (64, 512) int32
    const float* trans  = (const float*)d_in[2];   // (512, 512) fp32
    float* out = (float*)d_out;

    // zero numerator accumulator + done counter + tagged slot buffers (valid tags 1..512)
    hipMemsetAsync(d_ws, 0, WS_BYTES, stream);

    crf_fused<<<NB, BT, 0, stream>>>(inputs, tags, trans, d_ws, out);
}